// Round 1
// baseline (177.479 us; speedup 1.0000x reference)
//
#include <hip/hip_runtime.h>

typedef __attribute__((ext_vector_type(8))) short bf16x8;
typedef __attribute__((ext_vector_type(4))) float f32x4;

#define NB 8  // batches per block

#define A3  0.33333334f
#define B4  0.25f
#define C34 0.28867513f

// Per-row sparse A_hat: up to 4 (neighbor, weight) pairs; padded with weight 0.
__device__ const int ADJ_IDX[16][4] = {
  {0,1,7,0},{1,0,2,8},{2,1,3,9},{3,2,4,10},
  {4,3,5,11},{5,4,6,12},{6,5,13,0},{7,0,8,0},
  {8,7,9,1},{9,8,10,2},{10,9,11,3},{11,10,12,4},
  {12,11,13,5},{13,12,6,0},{0,0,0,0},{0,0,0,0}
};
__device__ const float ADJ_W[16][4] = {
  {A3,C34,A3,0.f},{B4,C34,B4,B4},{B4,B4,B4,B4},{B4,B4,B4,B4},
  {B4,B4,B4,B4},{B4,B4,C34,B4},{A3,C34,A3,0.f},{A3,A3,C34,0.f},
  {B4,C34,B4,B4},{B4,B4,B4,B4},{B4,B4,B4,B4},{B4,B4,B4,B4},
  {B4,B4,C34,B4},{A3,C34,A3,0.f},{0.f,0.f,0.f,0.f},{0.f,0.f,0.f,0.f}
};

__device__ __forceinline__ unsigned short f2b(float x) {
  unsigned u = __builtin_bit_cast(unsigned, x);
  u += 0x7FFFu + ((u >> 16) & 1u);   // round-to-nearest-even bf16
  return (unsigned short)(u >> 16);
}

__global__ __launch_bounds__(256) void fpm_kernel(
    const float* __restrict__ X, const float* __restrict__ W1,
    const float* __restrict__ b1, const float* __restrict__ W2,
    const float* __restrict__ b2, float* __restrict__ out, int Btot)
{
  // Xm (A*X) in bf16, MFMA A-fragment friendly row-major [16][256], XOR-swizzled
  __shared__ __align__(16) unsigned short XmL[16 * 256];
  // H1 = relu(Xm*W1 + b1), bf16 row-major [16][128], XOR-swizzled
  __shared__ __align__(16) unsigned short H1L[16 * 128];
  // C2 = H1*W2 staged col-major [64 cols][21 pad] f32
  __shared__ float C2T[64 * 21];

  const int tid  = threadIdx.x;
  const int lane = tid & 63;
  const int wv   = tid >> 6;     // wave id 0..3
  const int lrow = lane & 15;
  const int lgrp = lane >> 4;    // 0..3

  // ---- W1 B-fragments in registers: wave wv owns cols [32*wv, 32*wv+32) ----
  bf16x8 w1f[2][8];
  #pragma unroll
  for (int nt = 0; nt < 2; ++nt) {
    const int col = wv * 32 + nt * 16 + lrow;
    #pragma unroll
    for (int kk = 0; kk < 8; ++kk) {
      const int k0 = kk * 32 + lgrp * 8;
      bf16x8 f;
      #pragma unroll
      for (int j = 0; j < 8; ++j)
        ((unsigned short*)&f)[j] = f2b(W1[(k0 + j) * 128 + col]);
      w1f[nt][kk] = f;
    }
  }
  // ---- W2 B-fragments: wave wv owns cols [16*wv, 16*wv+16) ----
  bf16x8 w2f[4];
  {
    const int col = wv * 16 + lrow;
    #pragma unroll
    for (int kk = 0; kk < 4; ++kk) {
      const int k0 = kk * 32 + lgrp * 8;
      bf16x8 f;
      #pragma unroll
      for (int j = 0; j < 8; ++j)
        ((unsigned short*)&f)[j] = f2b(W2[(k0 + j) * 64 + col]);
      w2f[kk] = f;
    }
  }
  const float b1v0 = b1[wv * 32 + lrow];
  const float b1v1 = b1[wv * 32 + 16 + lrow];
  const float b2t  = b2[lane];

  // phase-A adjacency for this thread's fixed row r = tid&15
  const int ar = tid & 15;
  int   aidx[4];
  float aw[4];
  #pragma unroll
  for (int i = 0; i < 4; ++i) { aidx[i] = ADJ_IDX[ar][i] * 64; aw[i] = ADJ_W[ar][i]; }
  const bool arow_ok = (ar < 14);
  const int kw0 = tid >> 4;   // 0..15

  for (int bi = 0; bi < NB; ++bi) {
    const int b = blockIdx.x * NB + bi;
    if (b >= Btot) break;  // block-uniform
    const float4* Xb = (const float4*)(X + (size_t)b * (14 * 256));

    // ---------- Phase A: Xm = A_hat * X  -> bf16 swizzled LDS ----------
    #pragma unroll
    for (int half = 0; half < 2; ++half) {
      const int kw = kw0 + half * 16;      // 8-float window index 0..31
      float s0=0.f,s1=0.f,s2=0.f,s3=0.f,s4=0.f,s5=0.f,s6=0.f,s7=0.f;
      if (arow_ok) {
        #pragma unroll
        for (int i = 0; i < 4; ++i) {
          const float wt = aw[i];
          const float4 p = Xb[aidx[i] + kw * 2];
          const float4 q = Xb[aidx[i] + kw * 2 + 1];
          s0 = fmaf(wt, p.x, s0); s1 = fmaf(wt, p.y, s1);
          s2 = fmaf(wt, p.z, s2); s3 = fmaf(wt, p.w, s3);
          s4 = fmaf(wt, q.x, s4); s5 = fmaf(wt, q.y, s5);
          s6 = fmaf(wt, q.z, s6); s7 = fmaf(wt, q.w, s7);
        }
      }
      uint4 pk;
      pk.x = (unsigned)f2b(s0) | ((unsigned)f2b(s1) << 16);
      pk.y = (unsigned)f2b(s2) | ((unsigned)f2b(s3) << 16);
      pk.z = (unsigned)f2b(s4) | ((unsigned)f2b(s5) << 16);
      pk.w = (unsigned)f2b(s6) | ((unsigned)f2b(s7) << 16);
      *(uint4*)((char*)XmL + ((ar * 512 + kw * 16) ^ ((ar & 7) << 4))) = pk;
    }
    __syncthreads();

    // ---------- Phase B: GEMM1 (Xm * W1), bias+relu -> H1 ----------
    f32x4 acc10 = {0.f,0.f,0.f,0.f};
    f32x4 acc11 = {0.f,0.f,0.f,0.f};
    #pragma unroll
    for (int kk = 0; kk < 8; ++kk) {
      const bf16x8 a = *(const bf16x8*)((const char*)XmL +
          ((lrow * 512 + kk * 64 + lgrp * 16) ^ ((lrow & 7) << 4)));
      acc10 = __builtin_amdgcn_mfma_f32_16x16x32_bf16(a, w1f[0][kk], acc10, 0, 0, 0);
      acc11 = __builtin_amdgcn_mfma_f32_16x16x32_bf16(a, w1f[1][kk], acc11, 0, 0, 0);
    }
    #pragma unroll
    for (int j = 0; j < 4; ++j) {
      const int row = lgrp * 4 + j;
      const int swz = (row & 7) << 4;
      const float v0 = fmaxf(acc10[j] + b1v0, 0.f);
      const float v1 = fmaxf(acc11[j] + b1v1, 0.f);
      *(unsigned short*)((char*)H1L + ((row * 256 + (wv * 32 + lrow) * 2) ^ swz))      = f2b(v0);
      *(unsigned short*)((char*)H1L + ((row * 256 + (wv * 32 + 16 + lrow) * 2) ^ swz)) = f2b(v1);
    }
    __syncthreads();

    // ---------- Phase C: GEMM2 (H1 * W2) -> C2T ----------
    f32x4 acc2 = {0.f,0.f,0.f,0.f};
    #pragma unroll
    for (int kk = 0; kk < 4; ++kk) {
      const bf16x8 a = *(const bf16x8*)((const char*)H1L +
          ((lrow * 256 + kk * 64 + lgrp * 16) ^ ((lrow & 7) << 4)));
      acc2 = __builtin_amdgcn_mfma_f32_16x16x32_bf16(a, w2f[kk], acc2, 0, 0, 0);
    }
    {
      const int c = wv * 16 + lrow;
      #pragma unroll
      for (int j = 0; j < 4; ++j)
        C2T[c * 21 + lgrp * 4 + j] = acc2[j];
    }
    __syncthreads();

    // ---------- Phase D: out = A_hat * C2 + b2, store ----------
    {
      float* outB = out + (size_t)b * (14 * 64);
      const int col = lane;
      #pragma unroll
      for (int rr = 0; rr < 4; ++rr) {
        const int row = wv + rr * 4;     // wave-uniform
        if (row < 14) {
          float v = b2t;
          #pragma unroll
          for (int i = 0; i < 4; ++i)
            v = fmaf(ADJ_W[row][i], C2T[col * 21 + ADJ_IDX[row][i]], v);
          outB[row * 64 + col] = v;
        }
      }
    }
    // no trailing barrier: Phase D (reads C2T) overlaps next Phase A (writes XmL);
    // C2T is next written only after two more barriers.
  }
}

extern "C" void kernel_launch(void* const* d_in, const int* in_sizes, int n_in,
                              void* d_out, int out_size, void* d_ws, size_t ws_size,
                              hipStream_t stream) {
  (void)n_in; (void)out_size; (void)d_ws; (void)ws_size;
  const float* fea = (const float*)d_in[0];
  const float* W1  = (const float*)d_in[1];
  const float* b1  = (const float*)d_in[2];
  const float* W2  = (const float*)d_in[3];
  const float* b2  = (const float*)d_in[4];
  float* out = (float*)d_out;
  const int Btot = in_sizes[0] / (14 * 256);
  const int grid = (Btot + NB - 1) / NB;
  fpm_kernel<<<grid, 256, 0, stream>>>(fea, W1, b1, W2, b2, out, Btot);
}

// Round 2
// 109.222 us; speedup vs baseline: 1.6249x; 1.6249x over previous
//
#include <hip/hip_runtime.h>

typedef __attribute__((ext_vector_type(8))) short bf16x8;
typedef __attribute__((ext_vector_type(4))) float f32x4;

#define NB 4  // batches per block

#define A3  0.33333334f
#define B4  0.25f
#define C34 0.28867513f

// Per-row sparse A_hat: up to 4 (neighbor, weight) pairs; padded with weight 0.
__device__ const int ADJ_IDX[16][4] = {
  {0,1,7,0},{1,0,2,8},{2,1,3,9},{3,2,4,10},
  {4,3,5,11},{5,4,6,12},{6,5,13,0},{7,0,8,0},
  {8,7,9,1},{9,8,10,2},{10,9,11,3},{11,10,12,4},
  {12,11,13,5},{13,12,6,0},{0,0,0,0},{0,0,0,0}
};
__device__ const float ADJ_W[16][4] = {
  {A3,C34,A3,0.f},{B4,C34,B4,B4},{B4,B4,B4,B4},{B4,B4,B4,B4},
  {B4,B4,B4,B4},{B4,B4,C34,B4},{A3,C34,A3,0.f},{A3,A3,C34,0.f},
  {B4,C34,B4,B4},{B4,B4,B4,B4},{B4,B4,B4,B4},{B4,B4,B4,B4},
  {B4,B4,C34,B4},{A3,C34,A3,0.f},{0.f,0.f,0.f,0.f},{0.f,0.f,0.f,0.f}
};

__device__ __forceinline__ unsigned short f2b(float x) {
  unsigned u = __builtin_bit_cast(unsigned, x);
  u += 0x7FFFu + ((u >> 16) & 1u);   // round-to-nearest-even bf16
  return (unsigned short)(u >> 16);
}

// ---------- weight prep: build bf16 MFMA B-fragments into d_ws ----------
// layout: [0 .. 4096) fragments of W1: idx = ((wv*2+nt)*8+kk)*64 + lane
//         [4096 .. 5120) fragments of W2: idx = 4096 + (wv*4+kk)*64 + lane
// each fragment = 8 ushorts (16B)
__global__ __launch_bounds__(256) void prep_w(
    const float* __restrict__ W1, const float* __restrict__ W2,
    unsigned short* __restrict__ wf)
{
  const int f = blockIdx.x * 256 + threadIdx.x;   // 20 blocks -> 5120 frags
  unsigned short tmp[8];
  if (f < 4096) {
    const int lane = f & 63, kk = (f >> 6) & 7, nt = (f >> 9) & 1, wv = f >> 10;
    const int col = wv * 32 + nt * 16 + (lane & 15);
    const int k0  = kk * 32 + (lane >> 4) * 8;
    #pragma unroll
    for (int j = 0; j < 8; ++j) tmp[j] = f2b(W1[(k0 + j) * 128 + col]);
    *(uint4*)(wf + (size_t)f * 8) = *(const uint4*)tmp;
  } else if (f < 5120) {
    const int f2i = f - 4096;
    const int lane = f2i & 63, kk = (f2i >> 6) & 3, wv = f2i >> 8;
    const int col = wv * 16 + (lane & 15);
    const int k0  = kk * 32 + (lane >> 4) * 8;
    #pragma unroll
    for (int j = 0; j < 8; ++j) tmp[j] = f2b(W2[(k0 + j) * 64 + col]);
    *(uint4*)(wf + (size_t)f * 8) = *(const uint4*)tmp;
  }
}

#define XRAW_STRIDE_F 260   // floats per row (1040 B = 65*16B: 16B-aligned, 2-way banks)

__global__ __launch_bounds__(256) void fpm_kernel(
    const float* __restrict__ X,
    const unsigned short* __restrict__ wf, int use_wf,
    const float* __restrict__ W1, const float* __restrict__ W2,
    const float* __restrict__ b1, const float* __restrict__ b2,
    float* __restrict__ out, int Btot)
{
  __shared__ __align__(16) float XrawL[14 * XRAW_STRIDE_F + 12]; // raw X, f32
  __shared__ __align__(16) unsigned short XmL[16 * 256];  // A*X, bf16, swizzled
  __shared__ __align__(16) unsigned short H1L[16 * 128];  // relu layer1, bf16, swz
  __shared__ float C2T[64 * 21];                          // H1*W2 col-major

  const int tid  = threadIdx.x;
  const int lane = tid & 63;
  const int wv   = tid >> 6;
  const int lrow = lane & 15;
  const int lgrp = lane >> 4;

  // ---- weight fragments ----
  bf16x8 w1f[2][8];
  bf16x8 w2f[4];
  if (use_wf) {
    const bf16x8* wfv = (const bf16x8*)wf;
    #pragma unroll
    for (int nt = 0; nt < 2; ++nt)
      #pragma unroll
      for (int kk = 0; kk < 8; ++kk)
        w1f[nt][kk] = wfv[((wv * 2 + nt) * 8 + kk) * 64 + lane];
    #pragma unroll
    for (int kk = 0; kk < 4; ++kk)
      w2f[kk] = wfv[4096 + (wv * 4 + kk) * 64 + lane];
  } else {
    #pragma unroll
    for (int nt = 0; nt < 2; ++nt) {
      const int col = wv * 32 + nt * 16 + lrow;
      #pragma unroll
      for (int kk = 0; kk < 8; ++kk) {
        const int k0 = kk * 32 + lgrp * 8;
        bf16x8 f;
        #pragma unroll
        for (int j = 0; j < 8; ++j)
          ((unsigned short*)&f)[j] = f2b(W1[(k0 + j) * 128 + col]);
        w1f[nt][kk] = f;
      }
    }
    const int col = wv * 16 + lrow;
    #pragma unroll
    for (int kk = 0; kk < 4; ++kk) {
      const int k0 = kk * 32 + lgrp * 8;
      bf16x8 f;
      #pragma unroll
      for (int j = 0; j < 8; ++j)
        ((unsigned short*)&f)[j] = f2b(W2[(k0 + j) * 64 + col]);
      w2f[kk] = f;
    }
  }
  const float b1v0 = b1[wv * 32 + lrow];
  const float b1v1 = b1[wv * 32 + 16 + lrow];
  const float b2t  = b2[lane];

  // phase-A adjacency for this thread's row
  const int ar = tid & 15;
  int   abyte[4];
  float aw[4];
  #pragma unroll
  for (int i = 0; i < 4; ++i) {
    abyte[i] = ADJ_IDX[ar][i] * (XRAW_STRIDE_F * 4);
    aw[i]    = ADJ_W[ar][i];
  }
  const bool arow_ok = (ar < 14);
  const int kw0 = tid >> 4;   // 0..15

  const int b0 = blockIdx.x * NB;

  // staging registers (one batch of raw X: 896 float4 over 256 threads)
  float4 rg0, rg1, rg2, rg3;

  // ---- prologue: load batch b0, write to Xraw, load batch b0+1 ----
  if (b0 < Btot) {
    const float4* Xb4 = (const float4*)(X + (size_t)b0 * 3584);
    rg0 = Xb4[tid]; rg1 = Xb4[tid + 256]; rg2 = Xb4[tid + 512];
    if (tid < 128) rg3 = Xb4[tid + 768];
  }
  {
    // g = float4 index; row = g>>6, col4 = g&63; byte = row*1040 + col4*16
    int g0 = tid, g1 = tid + 256, g2 = tid + 512, g3 = tid + 768;
    *(float4*)((char*)XrawL + (g0 >> 6) * (XRAW_STRIDE_F * 4) + (g0 & 63) * 16) = rg0;
    *(float4*)((char*)XrawL + (g1 >> 6) * (XRAW_STRIDE_F * 4) + (g1 & 63) * 16) = rg1;
    *(float4*)((char*)XrawL + (g2 >> 6) * (XRAW_STRIDE_F * 4) + (g2 & 63) * 16) = rg2;
    if (tid < 128)
      *(float4*)((char*)XrawL + (g3 >> 6) * (XRAW_STRIDE_F * 4) + (g3 & 63) * 16) = rg3;
  }
  if (NB > 1 && b0 + 1 < Btot) {
    const float4* Xb4 = (const float4*)(X + (size_t)(b0 + 1) * 3584);
    rg0 = Xb4[tid]; rg1 = Xb4[tid + 256]; rg2 = Xb4[tid + 512];
    if (tid < 128) rg3 = Xb4[tid + 768];
  }
  __syncthreads();

  for (int bi = 0; bi < NB; ++bi) {
    const int b = b0 + bi;
    if (b >= Btot) break;  // block-uniform

    // ---------- Phase A: Xm = A_hat * Xraw -> bf16 swizzled LDS ----------
    #pragma unroll
    for (int half = 0; half < 2; ++half) {
      const int kw = kw0 + half * 16;      // 8-float window 0..31
      float s0=0.f,s1=0.f,s2=0.f,s3=0.f,s4=0.f,s5=0.f,s6=0.f,s7=0.f;
      if (arow_ok) {
        #pragma unroll
        for (int i = 0; i < 4; ++i) {
          const float wt = aw[i];
          const float4* rp = (const float4*)((const char*)XrawL + abyte[i] + kw * 32);
          const float4 p = rp[0];
          const float4 q = rp[1];
          s0 = fmaf(wt, p.x, s0); s1 = fmaf(wt, p.y, s1);
          s2 = fmaf(wt, p.z, s2); s3 = fmaf(wt, p.w, s3);
          s4 = fmaf(wt, q.x, s4); s5 = fmaf(wt, q.y, s5);
          s6 = fmaf(wt, q.z, s6); s7 = fmaf(wt, q.w, s7);
        }
      }
      uint4 pk;
      pk.x = (unsigned)f2b(s0) | ((unsigned)f2b(s1) << 16);
      pk.y = (unsigned)f2b(s2) | ((unsigned)f2b(s3) << 16);
      pk.z = (unsigned)f2b(s4) | ((unsigned)f2b(s5) << 16);
      pk.w = (unsigned)f2b(s6) | ((unsigned)f2b(s7) << 16);
      *(uint4*)((char*)XmL + ((ar * 512 + kw * 16) ^ ((ar & 7) << 4))) = pk;
    }
    __syncthreads();   // XmL ready; all waves done reading XrawL

    // ---------- staging: write batch b+1 to Xraw, start loads of b+2 ----------
    if (bi + 1 < NB && b + 1 < Btot) {
      int g0 = tid, g1 = tid + 256, g2 = tid + 512, g3 = tid + 768;
      *(float4*)((char*)XrawL + (g0 >> 6) * (XRAW_STRIDE_F * 4) + (g0 & 63) * 16) = rg0;
      *(float4*)((char*)XrawL + (g1 >> 6) * (XRAW_STRIDE_F * 4) + (g1 & 63) * 16) = rg1;
      *(float4*)((char*)XrawL + (g2 >> 6) * (XRAW_STRIDE_F * 4) + (g2 & 63) * 16) = rg2;
      if (tid < 128)
        *(float4*)((char*)XrawL + (g3 >> 6) * (XRAW_STRIDE_F * 4) + (g3 & 63) * 16) = rg3;
    }
    if (bi + 2 < NB && b + 2 < Btot) {
      const float4* Xb4 = (const float4*)(X + (size_t)(b + 2) * 3584);
      rg0 = Xb4[tid]; rg1 = Xb4[tid + 256]; rg2 = Xb4[tid + 512];
      if (tid < 128) rg3 = Xb4[tid + 768];
    }

    // ---------- Phase B: GEMM1 (Xm * W1), bias+relu -> H1 ----------
    f32x4 acc10 = {0.f,0.f,0.f,0.f};
    f32x4 acc11 = {0.f,0.f,0.f,0.f};
    #pragma unroll
    for (int kk = 0; kk < 8; ++kk) {
      const bf16x8 a = *(const bf16x8*)((const char*)XmL +
          ((lrow * 512 + kk * 64 + lgrp * 16) ^ ((lrow & 7) << 4)));
      acc10 = __builtin_amdgcn_mfma_f32_16x16x32_bf16(a, w1f[0][kk], acc10, 0, 0, 0);
      acc11 = __builtin_amdgcn_mfma_f32_16x16x32_bf16(a, w1f[1][kk], acc11, 0, 0, 0);
    }
    #pragma unroll
    for (int j = 0; j < 4; ++j) {
      const int row = lgrp * 4 + j;
      const int swz = (row & 7) << 4;
      const float v0 = fmaxf(acc10[j] + b1v0, 0.f);
      const float v1 = fmaxf(acc11[j] + b1v1, 0.f);
      *(unsigned short*)((char*)H1L + ((row * 256 + (wv * 32 + lrow) * 2) ^ swz))      = f2b(v0);
      *(unsigned short*)((char*)H1L + ((row * 256 + (wv * 32 + 16 + lrow) * 2) ^ swz)) = f2b(v1);
    }
    __syncthreads();   // H1L ready

    // ---------- Phase C: GEMM2 (H1 * W2) -> C2T ----------
    f32x4 acc2 = {0.f,0.f,0.f,0.f};
    #pragma unroll
    for (int kk = 0; kk < 4; ++kk) {
      const bf16x8 a = *(const bf16x8*)((const char*)H1L +
          ((lrow * 256 + kk * 64 + lgrp * 16) ^ ((lrow & 7) << 4)));
      acc2 = __builtin_amdgcn_mfma_f32_16x16x32_bf16(a, w2f[kk], acc2, 0, 0, 0);
    }
    {
      const int c = wv * 16 + lrow;
      #pragma unroll
      for (int j = 0; j < 4; ++j)
        C2T[c * 21 + lgrp * 4 + j] = acc2[j];
    }
    __syncthreads();   // C2T ready

    // ---------- Phase D: out = A_hat * C2 + b2 ----------
    {
      float* outB = out + (size_t)b * (14 * 64);
      const int col = lane;
      #pragma unroll
      for (int rr = 0; rr < 4; ++rr) {
        const int row = wv + rr * 4;     // wave-uniform
        if (row < 14) {
          float v = b2t;
          #pragma unroll
          for (int i = 0; i < 4; ++i)
            v = fmaf(ADJ_W[row][i], C2T[col * 21 + ADJ_IDX[row][i]], v);
          outB[row * 64 + col] = v;
        }
      }
    }
    // no trailing barrier: next Phase A reads Xraw (written before 2 barriers ago)
    // and writes XmL (last read before post-GEMM1 barrier). Safe.
  }
}

extern "C" void kernel_launch(void* const* d_in, const int* in_sizes, int n_in,
                              void* d_out, int out_size, void* d_ws, size_t ws_size,
                              hipStream_t stream) {
  (void)n_in; (void)out_size;
  const float* fea = (const float*)d_in[0];
  const float* W1  = (const float*)d_in[1];
  const float* b1  = (const float*)d_in[2];
  const float* W2  = (const float*)d_in[3];
  const float* b2  = (const float*)d_in[4];
  float* out = (float*)d_out;
  const int Btot = in_sizes[0] / (14 * 256);

  const size_t wf_bytes = 5120 * 16;
  const int use_wf = (ws_size >= wf_bytes) ? 1 : 0;
  unsigned short* wf = (unsigned short*)d_ws;
  if (use_wf) prep_w<<<20, 256, 0, stream>>>(W1, W2, wf);

  const int grid = (Btot + NB - 1) / NB;
  fpm_kernel<<<grid, 256, 0, stream>>>(fea, wf, use_wf, W1, W2, b1, b2, out, Btot);
}

// Round 3
// 106.788 us; speedup vs baseline: 1.6620x; 1.0228x over previous
//
#include <hip/hip_runtime.h>

typedef __attribute__((ext_vector_type(8))) short bf16x8;
typedef __attribute__((ext_vector_type(4))) float f32x4;

#define NB 4  // batches per block

#define A3  0.33333334f
#define B4  0.25f
#define C34 0.28867513f

// Per-row sparse A_hat: up to 4 (neighbor, weight) pairs; padded with weight 0.
__device__ const int ADJ_IDX[16][4] = {
  {0,1,7,0},{1,0,2,8},{2,1,3,9},{3,2,4,10},
  {4,3,5,11},{5,4,6,12},{6,5,13,0},{7,0,8,0},
  {8,7,9,1},{9,8,10,2},{10,9,11,3},{11,10,12,4},
  {12,11,13,5},{13,12,6,0},{0,0,0,0},{0,0,0,0}
};
__device__ const float ADJ_W[16][4] = {
  {A3,C34,A3,0.f},{B4,C34,B4,B4},{B4,B4,B4,B4},{B4,B4,B4,B4},
  {B4,B4,B4,B4},{B4,B4,C34,B4},{A3,C34,A3,0.f},{A3,A3,C34,0.f},
  {B4,C34,B4,B4},{B4,B4,B4,B4},{B4,B4,B4,B4},{B4,B4,B4,B4},
  {B4,B4,C34,B4},{A3,C34,A3,0.f},{0.f,0.f,0.f,0.f},{0.f,0.f,0.f,0.f}
};

__device__ __forceinline__ unsigned short f2b(float x) {
  unsigned u = __builtin_bit_cast(unsigned, x);
  u += 0x7FFFu + ((u >> 16) & 1u);   // round-to-nearest-even bf16
  return (unsigned short)(u >> 16);
}

// Raw barrier: orders LDS (lgkmcnt(0)) but does NOT drain vmcnt ->
// global prefetch loads stay in flight across it (the whole point).
#define BAR() do {                                        \
  __builtin_amdgcn_sched_barrier(0);                      \
  asm volatile("s_waitcnt lgkmcnt(0)" ::: "memory");      \
  __builtin_amdgcn_s_barrier();                           \
  __builtin_amdgcn_sched_barrier(0);                      \
} while (0)

// ---------- weight prep: build bf16 MFMA B-fragments into d_ws ----------
__global__ __launch_bounds__(256) void prep_w(
    const float* __restrict__ W1, const float* __restrict__ W2,
    unsigned short* __restrict__ wf)
{
  const int f = blockIdx.x * 256 + threadIdx.x;   // 20 blocks -> 5120 frags
  unsigned short tmp[8];
  if (f < 4096) {
    const int lane = f & 63, kk = (f >> 6) & 7, nt = (f >> 9) & 1, wv = f >> 10;
    const int col = wv * 32 + nt * 16 + (lane & 15);
    const int k0  = kk * 32 + (lane >> 4) * 8;
    #pragma unroll
    for (int j = 0; j < 8; ++j) tmp[j] = f2b(W1[(k0 + j) * 128 + col]);
    *(uint4*)(wf + (size_t)f * 8) = *(const uint4*)tmp;
  } else if (f < 5120) {
    const int f2i = f - 4096;
    const int lane = f2i & 63, kk = (f2i >> 6) & 3, wv = f2i >> 8;
    const int col = wv * 16 + (lane & 15);
    const int k0  = kk * 32 + (lane >> 4) * 8;
    #pragma unroll
    for (int j = 0; j < 8; ++j) tmp[j] = f2b(W2[(k0 + j) * 64 + col]);
    *(uint4*)(wf + (size_t)f * 8) = *(const uint4*)tmp;
  }
}

#define XRAW_STRIDE_F 260   // floats per row (1040 B: 16B-aligned, 2-way banks)

__global__ __launch_bounds__(256) void fpm_kernel(
    const float* __restrict__ X,
    const unsigned short* __restrict__ wf, int use_wf,
    const float* __restrict__ W1, const float* __restrict__ W2,
    const float* __restrict__ b1, const float* __restrict__ b2,
    float* __restrict__ out, int Btot)
{
  __shared__ __align__(16) float XrawL[14 * XRAW_STRIDE_F + 12]; // raw X, f32
  __shared__ __align__(16) unsigned short XmL[16 * 256];  // A*X, bf16, swizzled
  __shared__ __align__(16) unsigned short H1L[16 * 128];  // relu layer1, bf16, swz
  __shared__ float C2W[4 * 16 * 17];                      // wave-private C2 tiles

  const int tid  = threadIdx.x;
  const int lane = tid & 63;
  const int wv   = tid >> 6;
  const int lrow = lane & 15;
  const int lgrp = lane >> 4;

  // ---- weight fragments ----
  bf16x8 w1f[2][8];
  bf16x8 w2f[4];
  if (use_wf) {
    const bf16x8* wfv = (const bf16x8*)wf;
    #pragma unroll
    for (int nt = 0; nt < 2; ++nt)
      #pragma unroll
      for (int kk = 0; kk < 8; ++kk)
        w1f[nt][kk] = wfv[((wv * 2 + nt) * 8 + kk) * 64 + lane];
    #pragma unroll
    for (int kk = 0; kk < 4; ++kk)
      w2f[kk] = wfv[4096 + (wv * 4 + kk) * 64 + lane];
  } else {
    #pragma unroll
    for (int nt = 0; nt < 2; ++nt) {
      const int col = wv * 32 + nt * 16 + lrow;
      #pragma unroll
      for (int kk = 0; kk < 8; ++kk) {
        const int k0 = kk * 32 + lgrp * 8;
        bf16x8 f;
        #pragma unroll
        for (int j = 0; j < 8; ++j)
          ((unsigned short*)&f)[j] = f2b(W1[(k0 + j) * 128 + col]);
        w1f[nt][kk] = f;
      }
    }
    const int col = wv * 16 + lrow;
    #pragma unroll
    for (int kk = 0; kk < 4; ++kk) {
      const int k0 = kk * 32 + lgrp * 8;
      bf16x8 f;
      #pragma unroll
      for (int j = 0; j < 8; ++j)
        ((unsigned short*)&f)[j] = f2b(W2[(k0 + j) * 64 + col]);
      w2f[kk] = f;
    }
  }
  const float b1v0 = b1[wv * 32 + lrow];
  const float b1v1 = b1[wv * 32 + 16 + lrow];
  const float b2v  = b2[wv * 16 + lrow];

  // phase-A adjacency for this thread's row
  const int ar = tid & 15;
  int   abyte[4];
  float aw[4];
  #pragma unroll
  for (int i = 0; i < 4; ++i) {
    abyte[i] = ADJ_IDX[ar][i] * (XRAW_STRIDE_F * 4);
    aw[i]    = ADJ_W[ar][i];
  }
  const bool arow_ok = (ar < 14);
  const int kw0 = tid >> 4;   // 0..15

  const int b0 = blockIdx.x * NB;

  // staging registers (one batch of raw X: 896 float4 over 256 threads)
  float4 rg0, rg1, rg2, rg3;

  // ---- prologue: load batch b0, write to Xraw, start loads of b0+1 ----
  if (b0 < Btot) {
    const float4* Xb4 = (const float4*)(X + (size_t)b0 * 3584);
    rg0 = Xb4[tid]; rg1 = Xb4[tid + 256]; rg2 = Xb4[tid + 512];
    if (tid < 128) rg3 = Xb4[tid + 768];
  }
  {
    int g0 = tid, g1 = tid + 256, g2 = tid + 512, g3 = tid + 768;
    *(float4*)((char*)XrawL + (g0 >> 6) * (XRAW_STRIDE_F * 4) + (g0 & 63) * 16) = rg0;
    *(float4*)((char*)XrawL + (g1 >> 6) * (XRAW_STRIDE_F * 4) + (g1 & 63) * 16) = rg1;
    *(float4*)((char*)XrawL + (g2 >> 6) * (XRAW_STRIDE_F * 4) + (g2 & 63) * 16) = rg2;
    if (tid < 128)
      *(float4*)((char*)XrawL + (g3 >> 6) * (XRAW_STRIDE_F * 4) + (g3 & 63) * 16) = rg3;
  }
  if (NB > 1 && b0 + 1 < Btot) {
    const float4* Xb4 = (const float4*)(X + (size_t)(b0 + 1) * 3584);
    rg0 = Xb4[tid]; rg1 = Xb4[tid + 256]; rg2 = Xb4[tid + 512];
    if (tid < 128) rg3 = Xb4[tid + 768];
  }
  BAR();   // Xraw(b0) visible to all

  for (int bi = 0; bi < NB; ++bi) {
    const int b = b0 + bi;
    if (b >= Btot) break;  // block-uniform

    // ---------- Phase A: Xm = A_hat * Xraw -> bf16 swizzled LDS ----------
    #pragma unroll
    for (int half = 0; half < 2; ++half) {
      const int kw = kw0 + half * 16;      // 8-float window 0..31
      float s0=0.f,s1=0.f,s2=0.f,s3=0.f,s4=0.f,s5=0.f,s6=0.f,s7=0.f;
      if (arow_ok) {
        #pragma unroll
        for (int i = 0; i < 4; ++i) {
          const float wt = aw[i];
          const float4* rp = (const float4*)((const char*)XrawL + abyte[i] + kw * 32);
          const float4 p = rp[0];
          const float4 q = rp[1];
          s0 = fmaf(wt, p.x, s0); s1 = fmaf(wt, p.y, s1);
          s2 = fmaf(wt, p.z, s2); s3 = fmaf(wt, p.w, s3);
          s4 = fmaf(wt, q.x, s4); s5 = fmaf(wt, q.y, s5);
          s6 = fmaf(wt, q.z, s6); s7 = fmaf(wt, q.w, s7);
        }
      }
      uint4 pk;
      pk.x = (unsigned)f2b(s0) | ((unsigned)f2b(s1) << 16);
      pk.y = (unsigned)f2b(s2) | ((unsigned)f2b(s3) << 16);
      pk.z = (unsigned)f2b(s4) | ((unsigned)f2b(s5) << 16);
      pk.w = (unsigned)f2b(s6) | ((unsigned)f2b(s7) << 16);
      *(uint4*)((char*)XmL + ((ar * 512 + kw * 16) ^ ((ar & 7) << 4))) = pk;
    }
    BAR();   // [barrier 1] XmL visible; all waves done reading XrawL

    // ---------- staging: write batch b+1 to Xraw, start loads of b+2 ----------
    // Safe: every wave passed barrier 1, so all Phase-A reads of XrawL done.
    // These ds_writes become visible at barrier 2 (lgkmcnt(0) there), before
    // the next iteration's Phase A reads them.
    if (bi + 1 < NB && b + 1 < Btot) {
      int g0 = tid, g1 = tid + 256, g2 = tid + 512, g3 = tid + 768;
      *(float4*)((char*)XrawL + (g0 >> 6) * (XRAW_STRIDE_F * 4) + (g0 & 63) * 16) = rg0;
      *(float4*)((char*)XrawL + (g1 >> 6) * (XRAW_STRIDE_F * 4) + (g1 & 63) * 16) = rg1;
      *(float4*)((char*)XrawL + (g2 >> 6) * (XRAW_STRIDE_F * 4) + (g2 & 63) * 16) = rg2;
      if (tid < 128)
        *(float4*)((char*)XrawL + (g3 >> 6) * (XRAW_STRIDE_F * 4) + (g3 & 63) * 16) = rg3;
    }
    if (bi + 2 < NB && b + 2 < Btot) {
      // vmcnt is NOT drained by BAR(): these overlap all remaining phases.
      const float4* Xb4 = (const float4*)(X + (size_t)(b + 2) * 3584);
      rg0 = Xb4[tid]; rg1 = Xb4[tid + 256]; rg2 = Xb4[tid + 512];
      if (tid < 128) rg3 = Xb4[tid + 768];
    }

    // ---------- Phase B: GEMM1 (Xm * W1), bias+relu -> H1 ----------
    f32x4 acc10 = {0.f,0.f,0.f,0.f};
    f32x4 acc11 = {0.f,0.f,0.f,0.f};
    #pragma unroll
    for (int kk = 0; kk < 8; ++kk) {
      const bf16x8 a = *(const bf16x8*)((const char*)XmL +
          ((lrow * 512 + kk * 64 + lgrp * 16) ^ ((lrow & 7) << 4)));
      acc10 = __builtin_amdgcn_mfma_f32_16x16x32_bf16(a, w1f[0][kk], acc10, 0, 0, 0);
      acc11 = __builtin_amdgcn_mfma_f32_16x16x32_bf16(a, w1f[1][kk], acc11, 0, 0, 0);
    }
    #pragma unroll
    for (int j = 0; j < 4; ++j) {
      const int row = lgrp * 4 + j;
      const int swz = (row & 7) << 4;
      const float v0 = fmaxf(acc10[j] + b1v0, 0.f);
      const float v1 = fmaxf(acc11[j] + b1v1, 0.f);
      *(unsigned short*)((char*)H1L + ((row * 256 + (wv * 32 + lrow) * 2) ^ swz))      = f2b(v0);
      *(unsigned short*)((char*)H1L + ((row * 256 + (wv * 32 + 16 + lrow) * 2) ^ swz)) = f2b(v1);
    }
    BAR();   // [barrier 2] H1L + Xraw(b+1) visible; all done reading XmL

    // ---------- Phase C: GEMM2 (H1 * W2) -> wave-private C2 tile ----------
    f32x4 acc2 = {0.f,0.f,0.f,0.f};
    #pragma unroll
    for (int kk = 0; kk < 4; ++kk) {
      const bf16x8 a = *(const bf16x8*)((const char*)H1L +
          ((lrow * 256 + kk * 64 + lgrp * 16) ^ ((lrow & 7) << 4)));
      acc2 = __builtin_amdgcn_mfma_f32_16x16x32_bf16(a, w2f[kk], acc2, 0, 0, 0);
    }
    float* cw = &C2W[wv * (16 * 17)];
    #pragma unroll
    for (int j = 0; j < 4; ++j)
      cw[(lgrp * 4 + j) * 17 + lrow] = acc2[j];
    // wave-internal RAW on C2W: order ds ops explicitly (no cross-wave dep)
    __builtin_amdgcn_sched_barrier(0);
    asm volatile("s_waitcnt lgkmcnt(0)" ::: "memory");
    __builtin_amdgcn_sched_barrier(0);

    // ---------- Phase D: out = A_hat * C2 + b2 (wave-private, no barrier) ----
    {
      float* outB = out + (size_t)b * 896 + wv * 16;
      #pragma unroll
      for (int j = 0; j < 4; ++j) {
        const int row = lgrp * 4 + j;   // 0..15, lane-group dependent
        if (row < 14) {
          float v = b2v;
          #pragma unroll
          for (int i = 0; i < 4; ++i)
            v = fmaf(ADJ_W[row][i], cw[ADJ_IDX[row][i] * 17 + lrow], v);
          outB[row * 64 + lrow] = v;
        }
      }
    }
    // Next iter's Phase A: writes XmL (all reads of XmL ended before barrier 2),
    // reads Xraw(b+1) (visible at barrier 2). C2W/H1L reuse is ordered by
    // program order + barrier 2 of the next iteration. Safe with 2 barriers.
  }
}

extern "C" void kernel_launch(void* const* d_in, const int* in_sizes, int n_in,
                              void* d_out, int out_size, void* d_ws, size_t ws_size,
                              hipStream_t stream) {
  (void)n_in; (void)out_size;
  const float* fea = (const float*)d_in[0];
  const float* W1  = (const float*)d_in[1];
  const float* b1  = (const float*)d_in[2];
  const float* W2  = (const float*)d_in[3];
  const float* b2  = (const float*)d_in[4];
  float* out = (float*)d_out;
  const int Btot = in_sizes[0] / (14 * 256);

  const size_t wf_bytes = 5120 * 16;
  const int use_wf = (ws_size >= wf_bytes) ? 1 : 0;
  unsigned short* wf = (unsigned short*)d_ws;
  if (use_wf) prep_w<<<20, 256, 0, stream>>>(W1, W2, wf);

  const int grid = (Btot + NB - 1) / NB;
  fpm_kernel<<<grid, 256, 0, stream>>>(fea, wf, use_wf, W1, W2, b1, b2, out, Btot);
}

// Round 4
// 103.824 us; speedup vs baseline: 1.7094x; 1.0285x over previous
//
#include <hip/hip_runtime.h>

typedef __attribute__((ext_vector_type(8))) short bf16x8;
typedef __attribute__((ext_vector_type(4))) float f32x4;

#define NB 4  // batches per block

#define A3  0.33333334f
#define B4  0.25f
#define C34 0.28867513f

// Per-row sparse A_hat: up to 4 (neighbor, weight) pairs; padded with weight 0.
__device__ const int ADJ_IDX[16][4] = {
  {0,1,7,0},{1,0,2,8},{2,1,3,9},{3,2,4,10},
  {4,3,5,11},{5,4,6,12},{6,5,13,0},{7,0,8,0},
  {8,7,9,1},{9,8,10,2},{10,9,11,3},{11,10,12,4},
  {12,11,13,5},{13,12,6,0},{0,0,0,0},{0,0,0,0}
};
__device__ const float ADJ_W[16][4] = {
  {A3,C34,A3,0.f},{B4,C34,B4,B4},{B4,B4,B4,B4},{B4,B4,B4,B4},
  {B4,B4,B4,B4},{B4,B4,C34,B4},{A3,C34,A3,0.f},{A3,A3,C34,0.f},
  {B4,C34,B4,B4},{B4,B4,B4,B4},{B4,B4,B4,B4},{B4,B4,B4,B4},
  {B4,B4,C34,B4},{A3,C34,A3,0.f},{0.f,0.f,0.f,0.f},{0.f,0.f,0.f,0.f}
};

__device__ __forceinline__ unsigned short f2b(float x) {
  unsigned u = __builtin_bit_cast(unsigned, x);
  u += 0x7FFFu + ((u >> 16) & 1u);   // round-to-nearest-even bf16
  return (unsigned short)(u >> 16);
}

// Raw barrier: orders LDS (lgkmcnt(0)) but does NOT drain vmcnt ->
// global prefetch loads stay in flight across it.
#define BAR() do {                                        \
  __builtin_amdgcn_sched_barrier(0);                      \
  asm volatile("s_waitcnt lgkmcnt(0)" ::: "memory");      \
  __builtin_amdgcn_s_barrier();                           \
  __builtin_amdgcn_sched_barrier(0);                      \
} while (0)

// ---------- weight prep: build bf16 MFMA B-fragments into d_ws ----------
__global__ __launch_bounds__(256) void prep_w(
    const float* __restrict__ W1, const float* __restrict__ W2,
    unsigned short* __restrict__ wf)
{
  const int f = blockIdx.x * 256 + threadIdx.x;   // 20 blocks -> 5120 frags
  unsigned short tmp[8];
  if (f < 4096) {
    const int lane = f & 63, kk = (f >> 6) & 7, nt = (f >> 9) & 1, wv = f >> 10;
    const int col = wv * 32 + nt * 16 + (lane & 15);
    const int k0  = kk * 32 + (lane >> 4) * 8;
    #pragma unroll
    for (int j = 0; j < 8; ++j) tmp[j] = f2b(W1[(k0 + j) * 128 + col]);
    *(uint4*)(wf + (size_t)f * 8) = *(const uint4*)tmp;
  } else if (f < 5120) {
    const int f2i = f - 4096;
    const int lane = f2i & 63, kk = (f2i >> 6) & 3, wv = f2i >> 8;
    const int col = wv * 16 + (lane & 15);
    const int k0  = kk * 32 + (lane >> 4) * 8;
    #pragma unroll
    for (int j = 0; j < 8; ++j) tmp[j] = f2b(W2[(k0 + j) * 64 + col]);
    *(uint4*)(wf + (size_t)f * 8) = *(const uint4*)tmp;
  }
}

__global__ __launch_bounds__(256) void fpm_kernel(
    const float* __restrict__ X,
    const unsigned short* __restrict__ wf, int use_wf,
    const float* __restrict__ W1, const float* __restrict__ W2,
    const float* __restrict__ b1, const float* __restrict__ b2,
    float* __restrict__ out, int Btot)
{
  // X batch as bf16 MFMA-A fragments: row-major [16][256] bf16, XOR-swizzled
  __shared__ __align__(16) char XBF[16 * 512];
  // G = X*W1 staged col-major [128 cols][stride 80B]; bytes 0..32 = k0..15,
  // bytes 32..64 = zeros (k16..31 of the MFMA B-operand), 64..80 pad.
  __shared__ __align__(16) char GL[128 * 80];
  // H1 = relu(A*G + b1): row-major [16][128] bf16, XOR-swizzled
  __shared__ __align__(16) char H1B[16 * 256];
  // C2 = H1*W2 staged col-major [64 cols][stride 80B], zeros at 32..64
  __shared__ __align__(16) char C2B[64 * 80];

  const int tid  = threadIdx.x;
  const int lane = tid & 63;
  const int wv   = tid >> 6;
  const int lrow = lane & 15;
  const int lgrp = lane >> 4;

  // ---- weight fragments ----
  bf16x8 w1f[2][8];
  bf16x8 w2f[4];
  if (use_wf) {
    const bf16x8* wfv = (const bf16x8*)wf;
    #pragma unroll
    for (int nt = 0; nt < 2; ++nt)
      #pragma unroll
      for (int kk = 0; kk < 8; ++kk)
        w1f[nt][kk] = wfv[((wv * 2 + nt) * 8 + kk) * 64 + lane];
    #pragma unroll
    for (int kk = 0; kk < 4; ++kk)
      w2f[kk] = wfv[4096 + (wv * 4 + kk) * 64 + lane];
  } else {
    #pragma unroll
    for (int nt = 0; nt < 2; ++nt) {
      const int col = wv * 32 + nt * 16 + lrow;
      #pragma unroll
      for (int kk = 0; kk < 8; ++kk) {
        const int k0 = kk * 32 + lgrp * 8;
        bf16x8 f;
        #pragma unroll
        for (int j = 0; j < 8; ++j)
          ((unsigned short*)&f)[j] = f2b(W1[(k0 + j) * 128 + col]);
        w1f[nt][kk] = f;
      }
    }
    const int col = wv * 16 + lrow;
    #pragma unroll
    for (int kk = 0; kk < 4; ++kk) {
      const int k0 = kk * 32 + lgrp * 8;
      bf16x8 f;
      #pragma unroll
      for (int j = 0; j < 8; ++j)
        ((unsigned short*)&f)[j] = f2b(W2[(k0 + j) * 64 + col]);
      w2f[kk] = f;
    }
  }
  const float b1v0 = b1[wv * 32 + lrow];
  const float b1v1 = b1[wv * 32 + 16 + lrow];
  const float b2v  = b2[wv * 16 + lrow];

  // ---- A_hat as a constant MFMA A-fragment (16x16x32, k>=14 zero) ----
  bf16x8 amixf;
  #pragma unroll
  for (int j = 0; j < 8; ++j) {
    const int k = lgrp * 8 + j;
    float v = 0.f;
    #pragma unroll
    for (int i = 0; i < 4; ++i)
      if (ADJ_IDX[lrow][i] == k) v += ADJ_W[lrow][i];
    if (k >= 14) v = 0.f;
    ((unsigned short*)&amixf)[j] = f2b(v);
  }

  // ---- prologue zeroing (visible after first BAR) ----
  {
    // GL zero region: 128 cols x bytes[32,64)
    const int c = tid >> 1, off = 32 + (tid & 1) * 16;
    *(uint4*)(GL + c * 80 + off) = uint4{0, 0, 0, 0};
    if (tid < 128) {  // C2B zero region: 64 cols x bytes[32,64)
      const int c2 = tid >> 1;
      *(uint4*)(C2B + c2 * 80 + off) = uint4{0, 0, 0, 0};
    }
    if (tid < 64) {   // XBF rows 14,15 = 0 (swizzle-aware)
      const int row = 14 + (tid >> 5), c16 = tid & 31;
      *(uint4*)(XBF + ((row * 512 + c16 * 16) ^ ((row & 7) << 4))) = uint4{0, 0, 0, 0};
    }
  }

  const int b0 = blockIdx.x * NB;
  float4 rg0, rg1, rg2, rg3;   // staging regs: one batch = 896 float4 / 256 thr

  // stage-write helper: float4 -> 4 bf16 (8B) into XBF fragment layout
  auto stageWrite = [&](int g, float4 v) {
    const int row = g >> 6, i8 = g & 63;
    uint2 p;
    p.x = (unsigned)f2b(v.x) | ((unsigned)f2b(v.y) << 16);
    p.y = (unsigned)f2b(v.z) | ((unsigned)f2b(v.w) << 16);
    *(uint2*)(XBF + ((row * 512 + i8 * 8) ^ ((row & 7) << 4))) = p;
  };

  // ---- prologue: load b0 -> stage, issue loads of b0+1 ----
  if (b0 < Btot) {
    const float4* Xb4 = (const float4*)(X + (size_t)b0 * 3584);
    rg0 = Xb4[tid]; rg1 = Xb4[tid + 256]; rg2 = Xb4[tid + 512];
    if (tid < 128) rg3 = Xb4[tid + 768];
  }
  stageWrite(tid, rg0); stageWrite(tid + 256, rg1); stageWrite(tid + 512, rg2);
  if (tid < 128) stageWrite(tid + 768, rg3);
  if (NB > 1 && b0 + 1 < Btot) {
    const float4* Xb4 = (const float4*)(X + (size_t)(b0 + 1) * 3584);
    rg0 = Xb4[tid]; rg1 = Xb4[tid + 256]; rg2 = Xb4[tid + 512];
    if (tid < 128) rg3 = Xb4[tid + 768];
  }
  BAR();   // XBF(b0) + zero regions visible

  for (int bi = 0; bi < NB; ++bi) {
    const int b = b0 + bi;
    if (b >= Btot) break;  // block-uniform

    // ---------- GEMM1: G = Xbf * W1 (wave's 32 cols) ----------
    f32x4 g0 = {0.f,0.f,0.f,0.f};
    f32x4 g1 = {0.f,0.f,0.f,0.f};
    #pragma unroll
    for (int kk = 0; kk < 8; ++kk) {
      const bf16x8 a = *(const bf16x8*)(XBF +
          ((lrow * 512 + kk * 64 + lgrp * 16) ^ ((lrow & 7) << 4)));
      g0 = __builtin_amdgcn_mfma_f32_16x16x32_bf16(a, w1f[0][kk], g0, 0, 0, 0);
      g1 = __builtin_amdgcn_mfma_f32_16x16x32_bf16(a, w1f[1][kk], g1, 0, 0, 0);
    }
    // G -> LDS (wave-private cols, col-major, k = lgrp*4+j packed as b64)
    {
      uint2 p0, p1;
      p0.x = (unsigned)f2b(g0[0]) | ((unsigned)f2b(g0[1]) << 16);
      p0.y = (unsigned)f2b(g0[2]) | ((unsigned)f2b(g0[3]) << 16);
      p1.x = (unsigned)f2b(g1[0]) | ((unsigned)f2b(g1[1]) << 16);
      p1.y = (unsigned)f2b(g1[2]) | ((unsigned)f2b(g1[3]) << 16);
      *(uint2*)(GL + (wv * 32 + lrow) * 80 + lgrp * 8)      = p0;
      *(uint2*)(GL + (wv * 32 + 16 + lrow) * 80 + lgrp * 8) = p1;
    }
    // ---------- mix1: H1 = relu(Amix*G + b1) (wave-private, no barrier) ----
    {
      const bf16x8 gb0 = *(const bf16x8*)(GL + (wv * 32 + lrow) * 80 + lgrp * 16);
      const bf16x8 gb1 = *(const bf16x8*)(GL + (wv * 32 + 16 + lrow) * 80 + lgrp * 16);
      f32x4 h0 = {b1v0, b1v0, b1v0, b1v0};
      f32x4 h1 = {b1v1, b1v1, b1v1, b1v1};
      h0 = __builtin_amdgcn_mfma_f32_16x16x32_bf16(amixf, gb0, h0, 0, 0, 0);
      h1 = __builtin_amdgcn_mfma_f32_16x16x32_bf16(amixf, gb1, h1, 0, 0, 0);
      #pragma unroll
      for (int j = 0; j < 4; ++j) {
        const int r = lgrp * 4 + j;
        const int swz = (r & 7) << 4;
        *(unsigned short*)(H1B + ((r * 256 + (wv * 32 + lrow) * 2) ^ swz)) =
            f2b(fmaxf(h0[j], 0.f));
        *(unsigned short*)(H1B + ((r * 256 + (wv * 32 + 16 + lrow) * 2) ^ swz)) =
            f2b(fmaxf(h1[j], 0.f));
      }
    }
    BAR();   // [barrier 1] H1B visible; all waves done reading XBF

    // ---------- stage b+1 into XBF; issue global loads of b+2 ----------
    if (bi + 1 < NB && b + 1 < Btot) {
      stageWrite(tid, rg0); stageWrite(tid + 256, rg1); stageWrite(tid + 512, rg2);
      if (tid < 128) stageWrite(tid + 768, rg3);
    }
    if (bi + 2 < NB && b + 2 < Btot) {
      const float4* Xb4 = (const float4*)(X + (size_t)(b + 2) * 3584);
      rg0 = Xb4[tid]; rg1 = Xb4[tid + 256]; rg2 = Xb4[tid + 512];
      if (tid < 128) rg3 = Xb4[tid + 768];
    }

    // ---------- GEMM2: C2 = H1 * W2 (wave's 16 cols) ----------
    f32x4 c2 = {0.f,0.f,0.f,0.f};
    #pragma unroll
    for (int kk = 0; kk < 4; ++kk) {
      const bf16x8 a = *(const bf16x8*)(H1B +
          ((lrow * 256 + kk * 64 + lgrp * 16) ^ ((lrow & 7) << 4)));
      c2 = __builtin_amdgcn_mfma_f32_16x16x32_bf16(a, w2f[kk], c2, 0, 0, 0);
    }
    // C2 -> LDS (wave-private col-major)
    {
      uint2 p;
      p.x = (unsigned)f2b(c2[0]) | ((unsigned)f2b(c2[1]) << 16);
      p.y = (unsigned)f2b(c2[2]) | ((unsigned)f2b(c2[3]) << 16);
      *(uint2*)(C2B + (wv * 16 + lrow) * 80 + lgrp * 8) = p;
    }
    // ---------- mix2: out = Amix*C2 + b2; store ----------
    {
      const bf16x8 cb = *(const bf16x8*)(C2B + (wv * 16 + lrow) * 80 + lgrp * 16);
      f32x4 o = {b2v, b2v, b2v, b2v};
      o = __builtin_amdgcn_mfma_f32_16x16x32_bf16(amixf, cb, o, 0, 0, 0);
      float* outB = out + (size_t)b * 896;
      #pragma unroll
      for (int j = 0; j < 4; ++j) {
        const int r = lgrp * 4 + j;
        if (r < 14) outB[r * 64 + wv * 16 + lrow] = o[j];
      }
    }
    BAR();   // [barrier 2] XBF(b+1) visible; H1B reads done before next write
  }
}

extern "C" void kernel_launch(void* const* d_in, const int* in_sizes, int n_in,
                              void* d_out, int out_size, void* d_ws, size_t ws_size,
                              hipStream_t stream) {
  (void)n_in; (void)out_size;
  const float* fea = (const float*)d_in[0];
  const float* W1  = (const float*)d_in[1];
  const float* b1  = (const float*)d_in[2];
  const float* W2  = (const float*)d_in[3];
  const float* b2  = (const float*)d_in[4];
  float* out = (float*)d_out;
  const int Btot = in_sizes[0] / (14 * 256);

  const size_t wf_bytes = 5120 * 16;
  const int use_wf = (ws_size >= wf_bytes) ? 1 : 0;
  unsigned short* wf = (unsigned short*)d_ws;
  if (use_wf) prep_w<<<20, 256, 0, stream>>>(W1, W2, wf);

  const int grid = (Btot + NB - 1) / NB;
  fpm_kernel<<<grid, 256, 0, stream>>>(fea, wf, use_wf, W1, W2, b1, b2, out, Btot);
}

// Round 5
// 80.074 us; speedup vs baseline: 2.2164x; 1.2966x over previous
//
#include <hip/hip_runtime.h>

typedef __attribute__((ext_vector_type(8))) short bf16x8;
typedef __attribute__((ext_vector_type(4))) float f32x4;

#define NPW 4   // batches per wave

#define A3  0.33333334f
#define B4  0.25f
#define C34 0.28867513f

// Per-row sparse A_hat (includes diagonal): up to 4 (neighbor, weight) pairs.
__device__ const int ADJ_IDX[16][4] = {
  {0,1,7,0},{1,0,2,8},{2,1,3,9},{3,2,4,10},
  {4,3,5,11},{5,4,6,12},{6,5,13,0},{7,0,8,0},
  {8,7,9,1},{9,8,10,2},{10,9,11,3},{11,10,12,4},
  {12,11,13,5},{13,12,6,0},{0,0,0,0},{0,0,0,0}
};
__device__ const float ADJ_W[16][4] = {
  {A3,C34,A3,0.f},{B4,C34,B4,B4},{B4,B4,B4,B4},{B4,B4,B4,B4},
  {B4,B4,B4,B4},{B4,B4,C34,B4},{A3,C34,A3,0.f},{A3,A3,C34,0.f},
  {B4,C34,B4,B4},{B4,B4,B4,B4},{B4,B4,B4,B4},{B4,B4,B4,B4},
  {B4,B4,C34,B4},{A3,C34,A3,0.f},{0.f,0.f,0.f,0.f},{0.f,0.f,0.f,0.f}
};

__device__ __forceinline__ unsigned short f2b(float x) {
  unsigned u = __builtin_bit_cast(unsigned, x);
  u += 0x7FFFu + ((u >> 16) & 1u);   // RNE bf16
  return (unsigned short)(u >> 16);
}
__device__ __forceinline__ unsigned f2b2(float lo, float hi) {
  return (unsigned)f2b(lo) | ((unsigned)f2b(hi) << 16);
}

// ---------- weight prep: bf16 MFMA B-fragments into d_ws ----------
// W1: frag id (nt*8+kk), nt=0..8 (16-col tiles), kk=0..8 (K=32 tiles)
//     lane holds W1[kk*32+lgrp*8+j][nt*16+lrow], j=0..8  (16B/lane)
// W2: at 4096 + (nt*4+kt)*64, nt=0..4, kt=0..4, same per-lane layout.
__global__ __launch_bounds__(256) void prep_w(
    const float* __restrict__ W1, const float* __restrict__ W2,
    unsigned short* __restrict__ wf)
{
  const int f = blockIdx.x * 256 + threadIdx.x;   // 20 blocks -> 5120 frags
  unsigned short tmp[8];
  if (f < 4096) {
    const int lane = f & 63, kk = (f >> 6) & 7, nt = f >> 9;
    const int col = nt * 16 + (lane & 15);
    const int k0  = kk * 32 + (lane >> 4) * 8;
    #pragma unroll
    for (int j = 0; j < 8; ++j) tmp[j] = f2b(W1[(k0 + j) * 128 + col]);
    *(uint4*)(wf + (size_t)f * 8) = *(const uint4*)tmp;
  } else if (f < 5120) {
    const int f2i = f - 4096;
    const int lane = f2i & 63, kt = (f2i >> 6) & 3, nt = f2i >> 8;
    const int col = nt * 16 + (lane & 15);
    const int k0  = kt * 32 + (lane >> 4) * 8;
    #pragma unroll
    for (int j = 0; j < 8; ++j) tmp[j] = f2b(W2[(k0 + j) * 64 + col]);
    *(uint4*)(wf + (size_t)f * 8) = *(const uint4*)tmp;
  }
}

__global__ __launch_bounds__(512) void fpm_kernel(
    const float* __restrict__ X,
    const unsigned short* __restrict__ wf,
    const float* __restrict__ b1, const float* __restrict__ b2,
    float* __restrict__ out, int Btot)
{
  __shared__ __align__(16) uint4 WL[5120];   // 80 KiB: W1 frags [0,4096), W2 [4096,5120)

  const int tid  = threadIdx.x;
  const int lane = tid & 63;
  const int wv   = tid >> 6;      // 0..7
  const int lrow = lane & 15;
  const int lgrp = lane >> 4;

  // ---- one-time LDS fill (read-only afterwards) ----
  #pragma unroll
  for (int i = 0; i < 10; ++i)
    WL[i * 512 + tid] = ((const uint4*)wf)[i * 512 + tid];

  // ---- A_hat extended B-fragment: B[k][n]; k=14 row = 1.0 (bias row) ----
  bf16x8 amixB;
  #pragma unroll
  for (int jj = 0; jj < 8; ++jj) {
    const int k = lgrp * 8 + jj;
    float v = 0.f;
    if (k == 14) v = 1.f;
    else if (k < 14 && lrow < 14) {
      #pragma unroll
      for (int i = 0; i < 4; ++i)
        if (ADJ_IDX[k][i] == lrow) v += ADJ_W[k][i];
    }
    ((unsigned short*)&amixB)[jj] = f2b(v);
  }
  // bias values for injection at k=14 of the A-side fragment
  unsigned b1u[8], b2u[4];
  #pragma unroll
  for (int mt = 0; mt < 8; ++mt) b1u[mt] = (unsigned)f2b(b1[mt * 16 + lrow]);
  #pragma unroll
  for (int mt = 0; mt < 4; ++mt) b2u[mt] = (unsigned)f2b(b2[mt * 16 + lrow]);

  __syncthreads();   // the ONLY block-wide barrier

  const bf16x8* WLv = (const bf16x8*)WL;
  const f32x4 zacc = {0.f, 0.f, 0.f, 0.f};

  // cross-lane sources for the C/D -> A^T-fragment permutation
  const int srcA  = ((lrow + 32 * lgrp) & 63) * 4;        // valid for lgrp<2
  const int srcB  = ((lrow + 32 * lgrp + 16) & 63) * 4;
  const int srcA2 = (lrow + 32 * (lgrp & 1)) * 4;         // for GEMM2 A-frags
  const int srcB2 = srcA2 + 64;
  const bool hi2   = (lgrp >= 2);
  const bool isg1  = (lgrp == 1);

  const int gw    = blockIdx.x * 8 + wv;   // global wave id
  const int bbase = gw * NPW;

  float4 raw[16];
  #pragma unroll
  for (int i = 0; i < 16; ++i) raw[i] = float4{0.f, 0.f, 0.f, 0.f};
  if (bbase < Btot && lrow < 14) {
    const float* Xp = X + (size_t)bbase * 3584 + lrow * 256 + lgrp * 8;
    #pragma unroll
    for (int kk = 0; kk < 8; ++kk) {
      raw[2 * kk]     = *(const float4*)(Xp + kk * 32);
      raw[2 * kk + 1] = *(const float4*)(Xp + kk * 32 + 4);
    }
  }

  for (int bi = 0; bi < NPW; ++bi) {
    const int b = bbase + bi;
    if (b >= Btot) break;   // wave-uniform

    // ---- convert raw -> X A-fragments (rows 14,15 stay zero) ----
    bf16x8 xf[8];
    #pragma unroll
    for (int kk = 0; kk < 8; ++kk) {
      uint4 t;
      t.x = f2b2(raw[2 * kk].x,     raw[2 * kk].y);
      t.y = f2b2(raw[2 * kk].z,     raw[2 * kk].w);
      t.z = f2b2(raw[2 * kk + 1].x, raw[2 * kk + 1].y);
      t.w = f2b2(raw[2 * kk + 1].z, raw[2 * kk + 1].w);
      xf[kk] = __builtin_bit_cast(bf16x8, t);
    }
    // ---- prefetch next batch (in flight across the whole iteration) ----
    if (bi + 1 < NPW && b + 1 < Btot && lrow < 14) {
      const float* Xp = X + (size_t)(b + 1) * 3584 + lrow * 256 + lgrp * 8;
      #pragma unroll
      for (int kk = 0; kk < 8; ++kk) {
        raw[2 * kk]     = *(const float4*)(Xp + kk * 32);
        raw[2 * kk + 1] = *(const float4*)(Xp + kk * 32 + 4);
      }
    }

    // ---- GEMM1: G = Xb * W1  (M16 x N128 x K256) ----
    f32x4 acc1[8];
    #pragma unroll
    for (int nt = 0; nt < 8; ++nt) acc1[nt] = zacc;
    #pragma unroll
    for (int kk = 0; kk < 8; ++kk)
      #pragma unroll
      for (int nt = 0; nt < 8; ++nt)
        acc1[nt] = __builtin_amdgcn_mfma_f32_16x16x32_bf16(
            xf[kk], WLv[(nt * 8 + kk) * 64 + lane], acc1[nt], 0, 0, 0);

    // ---- mix1: H1^T = G^T * Ahat_ext  (bias via k=14 row) ----
    f32x4 h1t[8];
    #pragma unroll
    for (int mt = 0; mt < 8; ++mt) {
      const int p0 = (int)f2b2(acc1[mt][0], acc1[mt][1]);
      const int p1 = (int)f2b2(acc1[mt][2], acc1[mt][3]);
      int g0 = __builtin_amdgcn_ds_bpermute(srcA, p0);
      int g1 = __builtin_amdgcn_ds_bpermute(srcA, p1);
      int g2 = __builtin_amdgcn_ds_bpermute(srcB, p0);
      int g3 = __builtin_amdgcn_ds_bpermute(srcB, p1);
      if (hi2) { g0 = 0; g1 = 0; g2 = 0; g3 = 0; }           // k >= 16
      if (isg1) g3 = (int)(((unsigned)g3 & 0xFFFF0000u) | b1u[mt]);  // k=14 <- b1
      uint4 t; t.x = (unsigned)g0; t.y = (unsigned)g1;
      t.z = (unsigned)g2; t.w = (unsigned)g3;
      h1t[mt] = __builtin_amdgcn_mfma_f32_16x16x32_bf16(
          __builtin_bit_cast(bf16x8, t), amixB, zacc, 0, 0, 0);
    }

    // ---- relu + pack H1 (lane holds H1[row=lrow][cols mt*16+lgrp*4+j]) ----
    int h1p[8][2];
    #pragma unroll
    for (int mt = 0; mt < 8; ++mt) {
      h1p[mt][0] = (int)f2b2(fmaxf(h1t[mt][0], 0.f), fmaxf(h1t[mt][1], 0.f));
      h1p[mt][1] = (int)f2b2(fmaxf(h1t[mt][2], 0.f), fmaxf(h1t[mt][3], 0.f));
    }

    // ---- build GEMM2 A-fragments of H1 (K=128 -> 4 frags) ----
    bf16x8 a2[4];
    #pragma unroll
    for (int kt = 0; kt < 4; ++kt) {
      const int uA0 = __builtin_amdgcn_ds_bpermute(srcA2, h1p[2 * kt][0]);
      const int vA0 = __builtin_amdgcn_ds_bpermute(srcA2, h1p[2 * kt + 1][0]);
      const int uA1 = __builtin_amdgcn_ds_bpermute(srcA2, h1p[2 * kt][1]);
      const int vA1 = __builtin_amdgcn_ds_bpermute(srcA2, h1p[2 * kt + 1][1]);
      const int uB0 = __builtin_amdgcn_ds_bpermute(srcB2, h1p[2 * kt][0]);
      const int vB0 = __builtin_amdgcn_ds_bpermute(srcB2, h1p[2 * kt + 1][0]);
      const int uB1 = __builtin_amdgcn_ds_bpermute(srcB2, h1p[2 * kt][1]);
      const int vB1 = __builtin_amdgcn_ds_bpermute(srcB2, h1p[2 * kt + 1][1]);
      uint4 t;
      t.x = (unsigned)(hi2 ? vA0 : uA0);
      t.y = (unsigned)(hi2 ? vA1 : uA1);
      t.z = (unsigned)(hi2 ? vB0 : uB0);
      t.w = (unsigned)(hi2 ? vB1 : uB1);
      a2[kt] = __builtin_bit_cast(bf16x8, t);
    }

    // ---- GEMM2: C2 = H1 * W2  (M16 x N64 x K128) ----
    f32x4 acc2[4];
    #pragma unroll
    for (int nt = 0; nt < 4; ++nt) acc2[nt] = zacc;
    #pragma unroll
    for (int kt = 0; kt < 4; ++kt)
      #pragma unroll
      for (int nt = 0; nt < 4; ++nt)
        acc2[nt] = __builtin_amdgcn_mfma_f32_16x16x32_bf16(
            a2[kt], WLv[4096 + (nt * 4 + kt) * 64 + lane], acc2[nt], 0, 0, 0);

    // ---- mix2: out^T = C2^T * Ahat_ext (+b2 via k=14); store ----
    float* outB = out + (size_t)b * 896;
    #pragma unroll
    for (int mt = 0; mt < 4; ++mt) {
      const int p0 = (int)f2b2(acc2[mt][0], acc2[mt][1]);
      const int p1 = (int)f2b2(acc2[mt][2], acc2[mt][3]);
      int g0 = __builtin_amdgcn_ds_bpermute(srcA, p0);
      int g1 = __builtin_amdgcn_ds_bpermute(srcA, p1);
      int g2 = __builtin_amdgcn_ds_bpermute(srcB, p0);
      int g3 = __builtin_amdgcn_ds_bpermute(srcB, p1);
      if (hi2) { g0 = 0; g1 = 0; g2 = 0; g3 = 0; }
      if (isg1) g3 = (int)(((unsigned)g3 & 0xFFFF0000u) | b2u[mt]);  // k=14 <- b2
      uint4 t; t.x = (unsigned)g0; t.y = (unsigned)g1;
      t.z = (unsigned)g2; t.w = (unsigned)g3;
      const f32x4 o = __builtin_amdgcn_mfma_f32_16x16x32_bf16(
          __builtin_bit_cast(bf16x8, t), amixB, zacc, 0, 0, 0);
      if (lrow < 14) {
        float4 st; st.x = o[0]; st.y = o[1]; st.z = o[2]; st.w = o[3];
        *(float4*)(outB + lrow * 64 + mt * 16 + lgrp * 4) = st;
      }
    }
  }
}

extern "C" void kernel_launch(void* const* d_in, const int* in_sizes, int n_in,
                              void* d_out, int out_size, void* d_ws, size_t ws_size,
                              hipStream_t stream) {
  (void)n_in; (void)out_size; (void)ws_size;
  const float* fea = (const float*)d_in[0];
  const float* W1  = (const float*)d_in[1];
  const float* b1  = (const float*)d_in[2];
  const float* W2  = (const float*)d_in[3];
  const float* b2  = (const float*)d_in[4];
  float* out = (float*)d_out;
  const int Btot = in_sizes[0] / (14 * 256);

  unsigned short* wf = (unsigned short*)d_ws;    // ws_size >> 80KB (verified)
  prep_w<<<20, 256, 0, stream>>>(W1, W2, wf);

  const int per_block = 8 * NPW;
  const int grid = (Btot + per_block - 1) / per_block;
  fpm_kernel<<<grid, 512, 0, stream>>>(fea, wf, b1, b2, out, Btot);
}